// Round 9
// baseline (112.078 us; speedup 1.0000x reference)
//
#include <hip/hip_runtime.h>
#include <hip/hip_bf16.h>
#include <cstdint>
#include <cstddef>

// Problem dims (fixed): B=4, NI=NO=256, DIN=DQ=DH=DOUT=256.
// out[b,i,j,:] = gelu(u[b,i,:] + v[b,j,:]) @ W2 + b2
//   u = (x@W_pre + b_pre)@W1[:256] + b1   (b1 folded into u)
//   v = (query@W_emb + b_emb)@W1[256:]

typedef __bf16  bf16x8 __attribute__((ext_vector_type(8)));
typedef float   f32x16 __attribute__((ext_vector_type(16)));

// tanh-approx gelu with exp2 constant pre-folded:
// gelu(x) ~= x / (1 + exp2(x*(-2.3022072 - 0.1029433*x^2)))
__device__ __forceinline__ float fast_gelu(float x) {
    const float x2 = x * x;
    const float m  = __builtin_fmaf(x2, -0.1029433f, -2.3022072f);
    const float e  = __builtin_amdgcn_exp2f(x * m);
    return x * __builtin_amdgcn_rcpf(1.0f + e);
}

// ---------------------------------------------------------------------------
// Prep kernel (one launch) — unchanged from round 8 (passed).
// ---------------------------------------------------------------------------
__global__ __launch_bounds__(256) void prep_kernel(
    const float* __restrict__ x, const float* __restrict__ query,
    const float* __restrict__ W_pre, const float* __restrict__ b_pre,
    const float* __restrict__ W_emb, const float* __restrict__ b_emb,
    const float* __restrict__ W1, const float* __restrict__ b1,
    const float* __restrict__ W2,
    float* __restrict__ u, float* __restrict__ v,
    unsigned short* __restrict__ w2t)
{
    const int b = blockIdx.x;
    const int t = threadIdx.x;

    if (b >= 512) {                       // W2 transpose + bf16 convert
        const int n0 = (b - 512) * 4;
        const float4 wv = *reinterpret_cast<const float4*>(W2 + (size_t)t * 256 + n0);
        const float vals[4] = {wv.x, wv.y, wv.z, wv.w};
#pragma unroll
        for (int j = 0; j < 4; ++j) {
            const __bf16 bv = (__bf16)vals[j];
            w2t[(size_t)(n0 + j) * 256 + t] = __builtin_bit_cast(unsigned short, bv);
        }
        return;
    }

    const bool isq = (b >= 256);
    const float* __restrict__ A   = isq ? query : x;
    const float* __restrict__ Wa  = isq ? W_emb : W_pre;
    const float* __restrict__ ba  = isq ? b_emb : b_pre;
    const float* __restrict__ W1p = isq ? (W1 + 256 * 256) : W1;
    float* __restrict__ outp      = isq ? v : u;
    const int r0 = (isq ? (b - 256) : b) * 4;

    __shared__ float as[4][256];
    __shared__ float xs[4][256];

#pragma unroll
    for (int r = 0; r < 4; ++r)
        as[r][t] = A[(size_t)(r0 + r) * 256 + t];
    __syncthreads();

    float acc[4] = {0.f, 0.f, 0.f, 0.f};
    {
        float wcur[8];
#pragma unroll
        for (int q = 0; q < 8; ++q) wcur[q] = Wa[(size_t)q * 256 + t];
        for (int k0 = 0; k0 < 248; k0 += 8) {
            float wnxt[8];
#pragma unroll
            for (int q = 0; q < 8; ++q)
                wnxt[q] = Wa[(size_t)(k0 + 8 + q) * 256 + t];
#pragma unroll
            for (int q = 0; q < 8; ++q)
#pragma unroll
                for (int r = 0; r < 4; ++r)
                    acc[r] = __builtin_fmaf(as[r][k0 + q], wcur[q], acc[r]);
#pragma unroll
            for (int q = 0; q < 8; ++q) wcur[q] = wnxt[q];
        }
#pragma unroll
        for (int q = 0; q < 8; ++q)
#pragma unroll
            for (int r = 0; r < 4; ++r)
                acc[r] = __builtin_fmaf(as[r][248 + q], wcur[q], acc[r]);
    }
    const float bav = ba[t];
#pragma unroll
    for (int r = 0; r < 4; ++r) xs[r][t] = acc[r] + bav;
    __syncthreads();

    float acc2[4] = {0.f, 0.f, 0.f, 0.f};
    {
        float wcur[8];
#pragma unroll
        for (int q = 0; q < 8; ++q) wcur[q] = W1p[(size_t)q * 256 + t];
        for (int k0 = 0; k0 < 248; k0 += 8) {
            float wnxt[8];
#pragma unroll
            for (int q = 0; q < 8; ++q)
                wnxt[q] = W1p[(size_t)(k0 + 8 + q) * 256 + t];
#pragma unroll
            for (int q = 0; q < 8; ++q)
#pragma unroll
                for (int r = 0; r < 4; ++r)
                    acc2[r] = __builtin_fmaf(xs[r][k0 + q], wcur[q], acc2[r]);
#pragma unroll
            for (int q = 0; q < 8; ++q) wcur[q] = wnxt[q];
        }
#pragma unroll
        for (int q = 0; q < 8; ++q)
#pragma unroll
            for (int r = 0; r < 4; ++r)
                acc2[r] = __builtin_fmaf(xs[r][248 + q], wcur[q], acc2[r]);
    }
    const float b1v = isq ? 0.f : b1[t];
#pragma unroll
    for (int r = 0; r < 4; ++r)
        outp[(size_t)(r0 + r) * 256 + t] = acc2[r] + b1v;
}

// ---------------------------------------------------------------------------
// Fused main kernel — W2T staged ONCE, barrier-free K-loop, persistent tasks.
//
// 512 blocks (2/CU: LDS 80 KB), 256 threads = 4 waves. Block owns col-half
// ch = bid&1 (128 cols) and 8 tasks of 128 j-rows: P = (bid>>1)*8 + task,
// tile = P>>1 (b,i), jh = P&1. Wave w owns rows [w*32,+32) x 128 cols:
// acc = 4 x f32x16 = 64 VGPR.
//
// W2T col-half [128 n][256 k] bf16 = 64 KB staged ONCE per block via
// global_load_lds w16 (linear dest, inverse-swizzled source granule), then
// ONE __syncthreads for the whole kernel.
//
// Barrier-free K-loop: wave w's H rows (gelu(u+v), written via swizzled
// ds_write) are read back as A-frags by the SAME wave only -> intra-wave
// hazard, handled by program order + compiler lgkm waits. No cross-wave LDS
// dependency after the initial barrier -> 8 independent waves/CU; store
// drains of one wave overlap compute of others.
//
// vmcnt false-dep management (CDNA single in-order vmcnt): b2 hoisted before
// the task loop; next task's chunk-0 V/U loads issued BEFORE the epilogue
// stores (T14 issue-early) so the next gelu never waits on store drain.
// V register double-buffer (vvA/vvB), statically indexed (rule #20).
//
// mfma_f32_32x32x16_bf16 layouts (gfx950):
//   A: lane l holds A[l&31][(l>>5)*8 + e]
//   B: lane l holds B[(l>>5)*8 + e][l&31]
//   D: lane l reg r holds D[(r&3) + 8*(r>>2) + 4*(l>>5)][l&31]
// ---------------------------------------------------------------------------
__global__ __launch_bounds__(256, 2) void fused_kernel(
    const float* __restrict__ U, const float* __restrict__ V,
    const unsigned short* __restrict__ W2T, const float* __restrict__ b2,
    float* __restrict__ out)
{
    __shared__ uint4 wlds[4096];   // 64 KB: W2T half [128 n][32 g], swizzled
    __shared__ uint4 hlds[1024];   // 16 KB: H chunk  [128 r][8 g],  swizzled
    unsigned int* const h32 = reinterpret_cast<unsigned int*>(hlds);

    const int t    = threadIdx.x;
    const int lane = t & 63;
    const int w    = t >> 6;       // 0..3
    const int l31  = lane & 31;
    const int hi   = lane >> 5;    // 0..1
    const int d    = l31;          // k-pair index within chunk

    const int bid = blockIdx.x;
    const int ch  = bid & 1;
    const int grp = bid >> 1;      // 0..255
    const int n0  = ch * 128;

    // ---- stage W2T col-half ONCE (async, linear dest, pre-swizzled src) ----
#pragma unroll
    for (int it = 0; it < 16; ++it) {
        const int idx = it * 256 + t;          // linear LDS granule
        const int n   = idx >> 5;              // 0..127 local col
        const int gp  = idx & 31;              // LDS granule slot
        const int g   = (gp & 24) | ((gp ^ n) & 7);  // inverse-swizzled src
        __builtin_amdgcn_global_load_lds(
            (const __attribute__((address_space(1))) unsigned int*)
                (W2T + (size_t)(n0 + n) * 256 + g * 8),
            (__attribute__((address_space(3))) unsigned int*)(wlds + idx),
            16, 0, 0);
    }

    // hoist b2 (avoids per-task loads that would false-wait on store drain)
    float bvv[4];
#pragma unroll
    for (int cg = 0; cg < 4; ++cg) bvv[cg] = b2[n0 + cg * 32 + l31];

    float2 vvA[16], vvB[16];
    float2 u2A, u2B;
    const float* urow;
    const float* vrow;

    auto task_ptrs = [&](int task) {
        const int P    = grp * 8 + task;       // 0..2047
        const int tile = P >> 1;
        const int jh   = P & 1;
        const int bb   = tile >> 8;
        urow = U + (size_t)tile * 256;
        vrow = V + ((size_t)(bb * 256 + jh * 128)) * 256;
    };

    auto load_t = [&](int kk, float2& u2, float2 (&vv)[16]) {
        u2 = *reinterpret_cast<const float2*>(urow + kk + 2 * d);
#pragma unroll
        for (int p = 0; p < 16; ++p) {
            const int row = w * 32 + p * 2 + hi;   // 2 whole rows per instr
            vv[p] = *reinterpret_cast<const float2*>(
                vrow + (size_t)row * 256 + kk + 2 * d);
        }
    };

    auto gelu_write = [&](const float2& u2, const float2 (&vv)[16]) {
#pragma unroll
        for (int p = 0; p < 16; ++p) {
            const int row = w * 32 + p * 2 + hi;
            union { unsigned int u32; __bf16 h[2]; } pk;
            pk.h[0] = (__bf16)fast_gelu(u2.x + vv[p].x);
            pk.h[1] = (__bf16)fast_gelu(u2.y + vv[p].y);
            h32[row * 32 + (((d >> 2) ^ (row & 7)) << 2) + (d & 3)] = pk.u32;
        }
    };

    f32x16 acc[4];

    auto mfma_chunk = [&](int kk) {
        const int kg0 = kk >> 3;               // global granule base
#pragma unroll
        for (int s = 0; s < 4; ++s) {
            const int gl   = 2 * s + hi;       // local granule 0..7
            const int arow = w * 32 + l31;
            const bf16x8 afrag = __builtin_bit_cast(
                bf16x8, hlds[arow * 8 + (gl ^ (arow & 7))]);
            const int gk = kg0 + gl;           // global granule 0..31
#pragma unroll
            for (int cg = 0; cg < 4; ++cg) {
                const int nloc = cg * 32 + l31;
                const int slot = (gk & 24) | ((gk ^ nloc) & 7);
                const bf16x8 bfrag = __builtin_bit_cast(
                    bf16x8, wlds[nloc * 32 + slot]);
                acc[cg] = __builtin_amdgcn_mfma_f32_32x32x16_bf16(
                    afrag, bfrag, acc[cg], 0, 0, 0);
            }
        }
    };

    // prologue: prefetch task 0 / chunk 0
    task_ptrs(0);
    load_t(0, u2A, vvA);

    __syncthreads();   // drains W2T staging; the ONLY barrier in this kernel

    for (int task = 0; task < 8; ++task) {
#pragma unroll
        for (int i = 0; i < 4; ++i) acc[i] = (f32x16)0.f;

        // chunk 0: prefetch kk=64, consume A
        load_t(64, u2B, vvB);
        gelu_write(u2A, vvA);
        mfma_chunk(0);
        // chunk 1: prefetch kk=128, consume B
        load_t(128, u2A, vvA);
        gelu_write(u2B, vvB);
        mfma_chunk(64);
        // chunk 2: prefetch kk=192, consume A
        load_t(192, u2B, vvB);
        gelu_write(u2A, vvA);
        mfma_chunk(128);
        // chunk 3: prefetch NEXT task chunk 0 (before stores!), consume B
        const int P    = grp * 8 + task;
        const int tile = P >> 1;
        const int jh   = P & 1;
        if (task < 7) {
            task_ptrs(task + 1);
            load_t(0, u2A, vvA);
        }
        gelu_write(u2B, vvB);
        mfma_chunk(192);

        // epilogue: stores issued AFTER next-task prefetch -> no false dep
        const size_t obase = ((size_t)tile << 16) + (size_t)(jh * 128) * 256;
#pragma unroll
        for (int cg = 0; cg < 4; ++cg) {
            const int col = n0 + cg * 32 + l31;
#pragma unroll
            for (int rr = 0; rr < 16; ++rr) {
                const int row = w * 32 + 4 * hi + (rr & 3) + 8 * (rr >> 2);
                __builtin_nontemporal_store(acc[cg][rr] + bvv[cg],
                    out + obase + (size_t)row * 256 + col);
            }
        }
    }
}

// ---------------------------------------------------------------------------
extern "C" void kernel_launch(void* const* d_in, const int* in_sizes, int n_in,
                              void* d_out, int out_size, void* d_ws, size_t ws_size,
                              hipStream_t stream)
{
    const float* x     = (const float*)d_in[0];
    const float* query = (const float*)d_in[1];
    const float* W_pre = (const float*)d_in[2];
    const float* b_pre = (const float*)d_in[3];
    const float* W_emb = (const float*)d_in[4];
    const float* b_emb = (const float*)d_in[5];
    const float* W1    = (const float*)d_in[6];
    const float* b1    = (const float*)d_in[7];
    const float* W2    = (const float*)d_in[8];
    const float* b2    = (const float*)d_in[9];
    float* out = (float*)d_out;

    char* ws = (char*)d_ws;
    float* u            = (float*)(ws);                          // 1 MB
    float* v            = (float*)(ws + (1 << 20));              // 1 MB
    unsigned short* w2t = (unsigned short*)(ws + 2 * (1 << 20)); // 128 KB

    prep_kernel<<<576, 256, 0, stream>>>(x, query, W_pre, b_pre, W_emb, b_emb,
                                         W1, b1, W2, u, v, w2t);
    fused_kernel<<<512, 256, 0, stream>>>(u, v, w2t, b2, out);
}

// Round 10
// 100.843 us; speedup vs baseline: 1.1114x; 1.1114x over previous
//
#include <hip/hip_runtime.h>
#include <hip/hip_bf16.h>
#include <cstdint>
#include <cstddef>

// Problem dims (fixed): B=4, NI=NO=256, DIN=DQ=DH=DOUT=256.
// out[b,i,j,:] = gelu(u[b,i,:] + v[b,j,:]) @ W2 + b2
//   u = (x@W_pre + b_pre)@W1[:256] + b1   (b1 folded into u)
//   v = (query@W_emb + b_emb)@W1[256:]

typedef __bf16  bf16x8 __attribute__((ext_vector_type(8)));
typedef float   f32x16 __attribute__((ext_vector_type(16)));

// tanh-approx gelu with exp2 constant pre-folded:
// gelu(x) ~= x / (1 + exp2(x*(-2.3022072 - 0.1029433*x^2)))
__device__ __forceinline__ float fast_gelu(float x) {
    const float x2 = x * x;
    const float m  = __builtin_fmaf(x2, -0.1029433f, -2.3022072f);
    const float e  = __builtin_amdgcn_exp2f(x * m);
    return x * __builtin_amdgcn_rcpf(1.0f + e);
}

// ---------------------------------------------------------------------------
// Prep kernel (one launch) — unchanged from round 8 (passed, ~10 us).
// ---------------------------------------------------------------------------
__global__ __launch_bounds__(256) void prep_kernel(
    const float* __restrict__ x, const float* __restrict__ query,
    const float* __restrict__ W_pre, const float* __restrict__ b_pre,
    const float* __restrict__ W_emb, const float* __restrict__ b_emb,
    const float* __restrict__ W1, const float* __restrict__ b1,
    const float* __restrict__ W2,
    float* __restrict__ u, float* __restrict__ v,
    unsigned short* __restrict__ w2t)
{
    const int b = blockIdx.x;
    const int t = threadIdx.x;

    if (b >= 512) {                       // W2 transpose + bf16 convert
        const int n0 = (b - 512) * 4;
        const float4 wv = *reinterpret_cast<const float4*>(W2 + (size_t)t * 256 + n0);
        const float vals[4] = {wv.x, wv.y, wv.z, wv.w};
#pragma unroll
        for (int j = 0; j < 4; ++j) {
            const __bf16 bv = (__bf16)vals[j];
            w2t[(size_t)(n0 + j) * 256 + t] = __builtin_bit_cast(unsigned short, bv);
        }
        return;
    }

    const bool isq = (b >= 256);
    const float* __restrict__ A   = isq ? query : x;
    const float* __restrict__ Wa  = isq ? W_emb : W_pre;
    const float* __restrict__ ba  = isq ? b_emb : b_pre;
    const float* __restrict__ W1p = isq ? (W1 + 256 * 256) : W1;
    float* __restrict__ outp      = isq ? v : u;
    const int r0 = (isq ? (b - 256) : b) * 4;

    __shared__ float as[4][256];
    __shared__ float xs[4][256];

#pragma unroll
    for (int r = 0; r < 4; ++r)
        as[r][t] = A[(size_t)(r0 + r) * 256 + t];
    __syncthreads();

    float acc[4] = {0.f, 0.f, 0.f, 0.f};
    {
        float wcur[8];
#pragma unroll
        for (int q = 0; q < 8; ++q) wcur[q] = Wa[(size_t)q * 256 + t];
        for (int k0 = 0; k0 < 248; k0 += 8) {
            float wnxt[8];
#pragma unroll
            for (int q = 0; q < 8; ++q)
                wnxt[q] = Wa[(size_t)(k0 + 8 + q) * 256 + t];
#pragma unroll
            for (int q = 0; q < 8; ++q)
#pragma unroll
                for (int r = 0; r < 4; ++r)
                    acc[r] = __builtin_fmaf(as[r][k0 + q], wcur[q], acc[r]);
#pragma unroll
            for (int q = 0; q < 8; ++q) wcur[q] = wnxt[q];
        }
#pragma unroll
        for (int q = 0; q < 8; ++q)
#pragma unroll
            for (int r = 0; r < 4; ++r)
                acc[r] = __builtin_fmaf(as[r][248 + q], wcur[q], acc[r]);
    }
    const float bav = ba[t];
#pragma unroll
    for (int r = 0; r < 4; ++r) xs[r][t] = acc[r] + bav;
    __syncthreads();

    float acc2[4] = {0.f, 0.f, 0.f, 0.f};
    {
        float wcur[8];
#pragma unroll
        for (int q = 0; q < 8; ++q) wcur[q] = W1p[(size_t)q * 256 + t];
        for (int k0 = 0; k0 < 248; k0 += 8) {
            float wnxt[8];
#pragma unroll
            for (int q = 0; q < 8; ++q)
                wnxt[q] = W1p[(size_t)(k0 + 8 + q) * 256 + t];
#pragma unroll
            for (int q = 0; q < 8; ++q)
#pragma unroll
                for (int r = 0; r < 4; ++r)
                    acc2[r] = __builtin_fmaf(xs[r][k0 + q], wcur[q], acc2[r]);
#pragma unroll
            for (int q = 0; q < 8; ++q) wcur[q] = wnxt[q];
        }
#pragma unroll
        for (int q = 0; q < 8; ++q)
#pragma unroll
            for (int r = 0; r < 4; ++r)
                acc2[r] = __builtin_fmaf(xs[r][248 + q], wcur[q], acc2[r]);
    }
    const float b1v = isq ? 0.f : b1[t];
#pragma unroll
    for (int r = 0; r < 4; ++r)
        outp[(size_t)(r0 + r) * 256 + t] = acc2[r] + b1v;
}

// ---------------------------------------------------------------------------
// Fused main kernel — 4 waves/SIMD occupancy (the overlap lever).
//
// Block = 512 threads = 8 waves (2 row-halves x 4 col-quarters); block tile
// = 128 j-rows x 256 cols; 2048 blocks. Wave (wr,wc) owns 64r x 64c:
// acc = 2x2 x f32x16 = 64 VGPR -> total ~115 VGPR, fits the 128-VGPR cap of
// __launch_bounds__(512,4). LDS = W2T[256n][64k] 32 KB + H[128r][64k] 16 KB
// = 48 KB -> 2 blocks/CU = 16 waves/CU = 4 waves/SIMD (2x rounds 4-9).
// Rationale: per-pipe sums (VALU 17 + LDS 29 + HBM-W 43 + MFMA 3 us) ~= the
// observed ~95 us fused => pipes run serially; 4 waves/SIMD across 2
// independent blocks/CU provides the phase diversity to overlap them.
//
// Per 64-k chunk (2 barriers):
//   stage W2T chunk via global_load_lds w16 (linear dest, inverse-swizzled
//   source granule, G21); H = gelu(u+v) coalesced (lane -> k-pair, 2 whole
//   rows per wave-instr; 2 passes of 4 rows to cap VGPR), packed bf16x2
//   swizzled ds_write; barrier; 4 k-steps x (2 A + 2 B b128 reads + 4 MFMA)
//   = 1.0 b128/MFMA (vs 1.125 before); barrier.
//
// mfma_f32_32x32x16_bf16 layouts (gfx950):
//   A: lane l holds A[l&31][(l>>5)*8 + e]
//   B: lane l holds B[(l>>5)*8 + e][l&31]
//   D: lane l reg r holds D[(r&3) + 8*(r>>2) + 4*(l>>5)][l&31]
// ---------------------------------------------------------------------------
__global__ __launch_bounds__(512, 4) void fused_kernel(
    const float* __restrict__ U, const float* __restrict__ V,
    const unsigned short* __restrict__ W2T, const float* __restrict__ b2,
    float* __restrict__ out)
{
    __shared__ uint4 wlds[2048];   // 32 KB: W2T chunk [256 n][8 g], swizzled
    __shared__ uint4 hlds[1024];   // 16 KB: H tile    [128 r][8 g], swizzled
    unsigned int* const h32 = reinterpret_cast<unsigned int*>(hlds);

    const int t    = threadIdx.x;
    const int lane = t & 63;
    const int w    = t >> 6;       // 0..7
    const int l31  = lane & 31;
    const int hi   = lane >> 5;    // 0..1
    const int wr   = w >> 2;       // 0..1 row-half (64 rows)
    const int wc   = w & 3;        // 0..3 col-quarter (64 cols)

    const size_t r0 = (size_t)blockIdx.x * 128;
    const int bb = (int)(r0 >> 16);
    const int ii = (int)((r0 >> 8) & 255);
    const int j0 = (int)(r0 & 255);          // 0 or 128

    const float* __restrict__ urow  = U + ((size_t)(bb * 256 + ii)) * 256;
    const float* __restrict__ vbase = V + ((size_t)(bb * 256 + j0)) * 256;

    // H-compute mapping: d = k-pair (k = kk+2d, 2d+1), rb = row base 0..15.
    const int d  = t & 31;
    const int rb = t >> 5;

    f32x16 acc[2][2];
#pragma unroll
    for (int rg = 0; rg < 2; ++rg)
#pragma unroll
        for (int cg = 0; cg < 2; ++cg) acc[rg][cg] = (f32x16)0.f;

    for (int kk = 0; kk < 256; kk += 64) {
        // ---- stage W2T chunk (async, linear dest, pre-swizzled source) ----
#pragma unroll
        for (int it = 0; it < 4; ++it) {
            const int idx = it * 512 + t;    // linear LDS granule
            const int n   = idx >> 3;        // 0..255
            const int gp  = idx & 7;         // LDS granule slot
            const int g   = gp ^ (n & 7);    // inverse-swizzled source granule
            __builtin_amdgcn_global_load_lds(
                (const __attribute__((address_space(1))) unsigned int*)
                    (W2T + (size_t)n * 256 + kk + g * 8),
                (__attribute__((address_space(3))) unsigned int*)(wlds + idx),
                16, 0, 0);
        }

        // ---- H tile: coalesced loads, gelu once, swizzled ds_write ----
        const float2 u2 = *reinterpret_cast<const float2*>(urow + kk + 2 * d);
#pragma unroll 1
        for (int pass = 0; pass < 2; ++pass) {   // 2 passes of 4 rows: VGPR cap
            float2 vv[4];
#pragma unroll
            for (int p = 0; p < 4; ++p) {
                const int row = rb + (pass * 4 + p) * 16;
                vv[p] = *reinterpret_cast<const float2*>(
                    vbase + (size_t)row * 256 + kk + 2 * d);
            }
#pragma unroll
            for (int p = 0; p < 4; ++p) {
                const int row = rb + (pass * 4 + p) * 16;
                union { unsigned int u32; __bf16 h[2]; } pk;
                pk.h[0] = (__bf16)fast_gelu(u2.x + vv[p].x);
                pk.h[1] = (__bf16)fast_gelu(u2.y + vv[p].y);
                h32[row * 32 + (((d >> 2) ^ (row & 7)) << 2) + (d & 3)] = pk.u32;
            }
        }
        __syncthreads();   // drains gll (vmcnt) + H writes

        // ---- MFMA: 4 k-steps, 2 A + 2 B reads per step ----
#pragma unroll
        for (int s = 0; s < 4; ++s) {
            const int gk = 2 * s + hi;       // k-granule within chunk
            bf16x8 af[2];
#pragma unroll
            for (int rg = 0; rg < 2; ++rg) {
                const int arow = wr * 64 + rg * 32 + l31;
                af[rg] = __builtin_bit_cast(
                    bf16x8, hlds[arow * 8 + (gk ^ (arow & 7))]);
            }
#pragma unroll
            for (int cg = 0; cg < 2; ++cg) {
                const int col = wc * 64 + cg * 32 + l31;
                const bf16x8 bf_ = __builtin_bit_cast(
                    bf16x8, wlds[col * 8 + (gk ^ (col & 7))]);
#pragma unroll
                for (int rg = 0; rg < 2; ++rg)
                    acc[rg][cg] = __builtin_amdgcn_mfma_f32_32x32x16_bf16(
                        af[rg], bf_, acc[rg][cg], 0, 0, 0);
            }
        }
        __syncthreads();
    }

    // ---- epilogue: out[row][col] = acc + b2[col], nontemporal ----
#pragma unroll
    for (int rg = 0; rg < 2; ++rg) {
#pragma unroll
        for (int cg = 0; cg < 2; ++cg) {
            const int col = wc * 64 + cg * 32 + l31;
            const float bv = b2[col];
#pragma unroll
            for (int rr = 0; rr < 16; ++rr) {
                const int row = wr * 64 + rg * 32 + 4 * hi + (rr & 3) + 8 * (rr >> 2);
                __builtin_nontemporal_store(acc[rg][cg][rr] + bv,
                                            out + (r0 + row) * 256 + col);
            }
        }
    }
}

// ---------------------------------------------------------------------------
extern "C" void kernel_launch(void* const* d_in, const int* in_sizes, int n_in,
                              void* d_out, int out_size, void* d_ws, size_t ws_size,
                              hipStream_t stream)
{
    const float* x     = (const float*)d_in[0];
    const float* query = (const float*)d_in[1];
    const float* W_pre = (const float*)d_in[2];
    const float* b_pre = (const float*)d_in[3];
    const float* W_emb = (const float*)d_in[4];
    const float* b_emb = (const float*)d_in[5];
    const float* W1    = (const float*)d_in[6];
    const float* b1    = (const float*)d_in[7];
    const float* W2    = (const float*)d_in[8];
    const float* b2    = (const float*)d_in[9];
    float* out = (float*)d_out;

    char* ws = (char*)d_ws;
    float* u            = (float*)(ws);                          // 1 MB
    float* v            = (float*)(ws + (1 << 20));              // 1 MB
    unsigned short* w2t = (unsigned short*)(ws + 2 * (1 << 20)); // 128 KB

    prep_kernel<<<576, 256, 0, stream>>>(x, query, W_pre, b_pre, W_emb, b_emb,
                                         W1, b1, W2, u, v, w2t);
    fused_kernel<<<2048, 512, 0, stream>>>(u, v, w2t, b2, out);
}